// Round 2
// baseline (14103.107 us; speedup 1.0000x reference)
//
#include <hip/hip_runtime.h>

// Problem constants: B=4, DIM=192, H=W=256, HEADS=6, d=32, WS=8 -> 4096 windows x 64 tokens
#define NWIN 4096

__device__ __forceinline__ float bf2f(unsigned short u) {
    return __uint_as_float(((unsigned int)u) << 16);
}
__device__ __forceinline__ unsigned short f2bf(float f) {
    unsigned int x = __float_as_uint(f);
    x += 0x7fffu + ((x >> 16) & 1u);
    return (unsigned short)(x >> 16);
}
__device__ __forceinline__ float gelu_exact(float x) {
    return 0.5f * x * (1.0f + erff(x * 0.70710678118654752f));
}

// ---------------------------------------------------------------------------
// Fully fused block: LN1 + window attention + proj + shortcut + LN2 + MLP +
// residual.  One block per 8x8 window; MLP is token-local so no workspace.
// f32 global I/O; bf16 LDS staging for GEMM operands (error << 2% threshold;
// both residual adds are exact f32 in registers).
// ---------------------------------------------------------------------------
__global__ __launch_bounds__(256, 2) void fused_block_kernel(
    const float* __restrict__ x,      // (B,192,256,256)
    const float* __restrict__ bpe,    // (B,32,256,256)
    const float* __restrict__ ln1_w,
    const float* __restrict__ ln1_b,
    const float* __restrict__ qkv_w,  // (192,576)
    const float* __restrict__ qkv_b,  // (576)
    const float* __restrict__ bpe_w,  // (32,384)
    const float* __restrict__ bpe_b,  // (384)
    const float* __restrict__ proj_w, // (192,192)
    const float* __restrict__ proj_b, // (192)
    const float* __restrict__ ln2_w,
    const float* __restrict__ ln2_b,
    const float* __restrict__ fc1_w,  // (192,768)
    const float* __restrict__ fc1_b,  // (768)
    const float* __restrict__ fc2_w,  // (768,192)
    const float* __restrict__ fc2_b,  // (192)
    float* __restrict__ out)          // (B,192,256,256)
{
    __shared__ __align__(16) unsigned short xsb[64][200]; // LN1(x) bf16; later LN2(xh2)
    __shared__ __align__(16) unsigned short bsb[64][33];  // bpe tile
    __shared__ __align__(16) unsigned short qa[64][36];   // q, later v
    __shared__ __align__(16) unsigned short kb[64][36];   // k
    __shared__ __align__(16) unsigned short bqa[64][36];  // bq
    __shared__ __align__(16) unsigned short bkb[64][36];  // bk
    __shared__ __align__(16) unsigned short oh[64][36];   // head output
    __shared__ __align__(16) float at[64][65];            // scores; later gelu(fc1) as bf16
    __shared__ float sred[64][4];                         // LN2 partial sums
    __shared__ float s2red[64][4];

    const int tid = threadIdx.x;
    const int wid = blockIdx.x;
    const int b   = wid >> 10;
    const int rem = wid & 1023;
    const int h0  = (rem >> 5) << 3;
    const int w0  = (rem & 31) << 3;

    // ---- load x tile (64 tokens x 192 ch, f32 -> bf16) and bpe tile ----
    for (int e = tid; e < 64 * 192; e += 256) {
        int t = e & 63, c = e >> 6;
        int gi = b * (192 * 65536) + c * 65536 + (h0 + (t >> 3)) * 256 + (w0 + (t & 7));
        xsb[t][c] = f2bf(x[gi]);
    }
    for (int e = tid; e < 64 * 32; e += 256) {
        int t = e & 63, c = e >> 6;
        int gi = b * (32 * 65536) + c * 65536 + (h0 + (t >> 3)) * 256 + (w0 + (t & 7));
        bsb[t][c] = f2bf(bpe[gi]);
    }
    __syncthreads();

    // ---- LN1 (4 threads per token, intra-wave shuffle) ----
    {
        int t = tid >> 2, sub = tid & 3;
        float s = 0.f, s2 = 0.f;
        int c0 = sub * 48;
        #pragma unroll 4
        for (int c = c0; c < c0 + 48; ++c) {
            float v = bf2f(xsb[t][c]);
            s += v; s2 += v * v;
        }
        s  += __shfl_xor(s, 1);  s  += __shfl_xor(s, 2);
        s2 += __shfl_xor(s2, 1); s2 += __shfl_xor(s2, 2);
        float m    = s * (1.0f / 192.0f);
        float var  = s2 * (1.0f / 192.0f) - m * m;
        float rstd = rsqrtf(var + 1e-5f);
        #pragma unroll 4
        for (int c = c0; c < c0 + 48; ++c) {
            float v  = bf2f(xsb[t][c]);
            float nv = (v - m) * rstd * ln1_w[c] + ln1_b[c];
            xsb[t][c] = f2bf(nv);
        }
    }
    __syncthreads();

    float acc[48];                     // xh2 = shortcut + attn-out (f32, exact)
    #pragma unroll
    for (int j = 0; j < 48; ++j) acc[j] = 0.f;
    const int zt = tid & 63;           // owned token
    const int zz = tid >> 6;           // channel quarter

    const float scale = 0.17677669529663687f; // 1/sqrt(32)

    for (int h = 0; h < 6; ++h) {
        const int hb = h * 32;
        // ---- q, k, bq, bk ----
        for (int it = 0; it < 2; ++it) {
            int qd = it * 256 + tid;
            int dd = (qd & 7) << 2;
            int t  = qd >> 3;
            int qcol = hb + dd;
            float aq0 = 0, aq1 = 0, aq2 = 0, aq3 = 0;
            float ak0 = 0, ak1 = 0, ak2 = 0, ak3 = 0;
            #pragma unroll 4
            for (int c = 0; c < 192; ++c) {
                float xv = bf2f(xsb[t][c]);
                float4 wq = *(const float4*)(qkv_w + c * 576 + qcol);
                float4 wk = *(const float4*)(qkv_w + c * 576 + 192 + qcol);
                aq0 += xv * wq.x; aq1 += xv * wq.y; aq2 += xv * wq.z; aq3 += xv * wq.w;
                ak0 += xv * wk.x; ak1 += xv * wk.y; ak2 += xv * wk.z; ak3 += xv * wk.w;
            }
            aq0 += qkv_b[qcol];     aq1 += qkv_b[qcol + 1];
            aq2 += qkv_b[qcol + 2]; aq3 += qkv_b[qcol + 3];
            ak0 += qkv_b[192 + qcol];     ak1 += qkv_b[192 + qcol + 1];
            ak2 += qkv_b[192 + qcol + 2]; ak3 += qkv_b[192 + qcol + 3];
            qa[t][dd] = f2bf(aq0); qa[t][dd + 1] = f2bf(aq1);
            qa[t][dd + 2] = f2bf(aq2); qa[t][dd + 3] = f2bf(aq3);
            kb[t][dd] = f2bf(ak0); kb[t][dd + 1] = f2bf(ak1);
            kb[t][dd + 2] = f2bf(ak2); kb[t][dd + 3] = f2bf(ak3);

            float bq0 = 0, bq1 = 0, bq2 = 0, bq3 = 0;
            float bk0 = 0, bk1 = 0, bk2 = 0, bk3 = 0;
            #pragma unroll 4
            for (int c = 0; c < 32; ++c) {
                float bv = bf2f(bsb[t][c]);
                float4 wq = *(const float4*)(bpe_w + c * 384 + qcol);
                float4 wk = *(const float4*)(bpe_w + c * 384 + 192 + qcol);
                bq0 += bv * wq.x; bq1 += bv * wq.y; bq2 += bv * wq.z; bq3 += bv * wq.w;
                bk0 += bv * wk.x; bk1 += bv * wk.y; bk2 += bv * wk.z; bk3 += bv * wk.w;
            }
            bq0 += bpe_b[qcol];     bq1 += bpe_b[qcol + 1];
            bq2 += bpe_b[qcol + 2]; bq3 += bpe_b[qcol + 3];
            bk0 += bpe_b[192 + qcol];     bk1 += bpe_b[192 + qcol + 1];
            bk2 += bpe_b[192 + qcol + 2]; bk3 += bpe_b[192 + qcol + 3];
            bqa[t][dd] = f2bf(bq0); bqa[t][dd + 1] = f2bf(bq1);
            bqa[t][dd + 2] = f2bf(bq2); bqa[t][dd + 3] = f2bf(bq3);
            bkb[t][dd] = f2bf(bk0); bkb[t][dd + 1] = f2bf(bk1);
            bkb[t][dd + 2] = f2bf(bk2); bkb[t][dd + 3] = f2bf(bk3);
        }
        __syncthreads();

        // ---- scores = (q.kT + bq.bkT) * scale ----
        for (int it = 0; it < 16; ++it) {
            int e = it * 256 + tid;
            int j = e & 63, i = e >> 6;
            float s = 0.f;
            #pragma unroll
            for (int d = 0; d < 32; d += 4) {
                ushort4 qv = *(const ushort4*)&qa[i][d];
                ushort4 kv = *(const ushort4*)&kb[j][d];
                s += bf2f(qv.x) * bf2f(kv.x) + bf2f(qv.y) * bf2f(kv.y)
                   + bf2f(qv.z) * bf2f(kv.z) + bf2f(qv.w) * bf2f(kv.w);
                ushort4 bqv = *(const ushort4*)&bqa[i][d];
                ushort4 bkv = *(const ushort4*)&bkb[j][d];
                s += bf2f(bqv.x) * bf2f(bkv.x) + bf2f(bqv.y) * bf2f(bkv.y)
                   + bf2f(bqv.z) * bf2f(bkv.z) + bf2f(bqv.w) * bf2f(bkv.w);
            }
            at[i][j] = s * scale;
        }
        __syncthreads();

        // ---- softmax per row ----
        if (tid < 64) {
            int i = tid;
            float mx = -1e30f;
            #pragma unroll 4
            for (int j = 0; j < 64; ++j) mx = fmaxf(mx, at[i][j]);
            float sum = 0.f;
            #pragma unroll 4
            for (int j = 0; j < 64; ++j) {
                float p = __expf(at[i][j] - mx);
                at[i][j] = p;
                sum += p;
            }
            float inv = 1.0f / sum;
            #pragma unroll 4
            for (int j = 0; j < 64; ++j) at[i][j] *= inv;
        }
        __syncthreads();

        // ---- v (into qa; q no longer needed) ----
        for (int it = 0; it < 2; ++it) {
            int qd = it * 256 + tid;
            int dd = (qd & 7) << 2;
            int t  = qd >> 3;
            int vcol = 384 + hb + dd;
            float a0 = qkv_b[vcol],     a1 = qkv_b[vcol + 1];
            float a2 = qkv_b[vcol + 2], a3 = qkv_b[vcol + 3];
            #pragma unroll 4
            for (int c = 0; c < 192; ++c) {
                float xv = bf2f(xsb[t][c]);
                float4 wv = *(const float4*)(qkv_w + c * 576 + vcol);
                a0 += xv * wv.x; a1 += xv * wv.y; a2 += xv * wv.z; a3 += xv * wv.w;
            }
            qa[t][dd] = f2bf(a0); qa[t][dd + 1] = f2bf(a1);
            qa[t][dd + 2] = f2bf(a2); qa[t][dd + 3] = f2bf(a3);
        }
        __syncthreads();

        // ---- oh = attn @ v ----
        for (int it = 0; it < 2; ++it) {
            int qd = it * 256 + tid;
            int dd = (qd & 7) << 2;
            int t  = qd >> 3;
            float a0 = 0, a1 = 0, a2 = 0, a3 = 0;
            #pragma unroll 4
            for (int m = 0; m < 64; ++m) {
                float p = at[t][m];
                ushort4 vv = *(const ushort4*)&qa[m][dd];
                a0 += p * bf2f(vv.x); a1 += p * bf2f(vv.y);
                a2 += p * bf2f(vv.z); a3 += p * bf2f(vv.w);
            }
            oh[t][dd] = f2bf(a0); oh[t][dd + 1] = f2bf(a1);
            oh[t][dd + 2] = f2bf(a2); oh[t][dd + 3] = f2bf(a3);
        }
        __syncthreads();

        // ---- proj accumulation ----
        for (int d = 0; d < 32; ++d) {
            float ov = bf2f(oh[zt][d]);
            const float* wrow = proj_w + (hb + d) * 192 + zz * 48;
            #pragma unroll
            for (int j4 = 0; j4 < 48; j4 += 4) {
                float4 w = *(const float4*)(wrow + j4);
                acc[j4]     += ov * w.x;
                acc[j4 + 1] += ov * w.y;
                acc[j4 + 2] += ov * w.z;
                acc[j4 + 3] += ov * w.w;
            }
        }
        __syncthreads();
    }

    // ---- xh2 = attn-out + proj_b + shortcut (exact f32 in registers) ----
    const int gh = h0 + (zt >> 3), gw = w0 + (zt & 7);
    {
        const float* xrow = x + b * (192 * 65536) + gh * 256 + gw;
        #pragma unroll 4
        for (int j = 0; j < 48; ++j) {
            int c = zz * 48 + j;
            acc[j] += proj_b[c] + xrow[c * 65536];
        }
    }

    // ---- LN2: cross-wave partial reduction via LDS ----
    {
        float s = 0.f, s2 = 0.f;
        #pragma unroll 4
        for (int j = 0; j < 48; ++j) { s += acc[j]; s2 += acc[j] * acc[j]; }
        sred[zt][zz] = s; s2red[zt][zz] = s2;
    }
    __syncthreads();
    {
        float s  = sred[zt][0] + sred[zt][1] + sred[zt][2] + sred[zt][3];
        float s2 = s2red[zt][0] + s2red[zt][1] + s2red[zt][2] + s2red[zt][3];
        float m    = s * (1.0f / 192.0f);
        float var  = s2 * (1.0f / 192.0f) - m * m;
        float rstd = rsqrtf(var + 1e-5f);
        #pragma unroll 4
        for (int j = 0; j < 48; ++j) {
            int c = zz * 48 + j;
            xsb[zt][c] = f2bf((acc[j] - m) * rstd * ln2_w[c] + ln2_b[c]);
        }
    }
    __syncthreads();

    // ---- MLP: fc1 + gelu + fc2, hidden chunked by 128 ----
    float acc2[48];
    #pragma unroll
    for (int j = 0; j < 48; ++j) acc2[j] = 0.f;
    unsigned short* hs = (unsigned short*)&at[0][0]; // 64 x 130 bf16 overlay (16640 B)

    for (int cn = 0; cn < 6; ++cn) {
        {
            int jj = (tid & 31) << 2;
            int tb = tid >> 5;
            const float* wcol = fc1_w + cn * 128 + jj;
            for (int it = 0; it < 8; ++it) {
                int t = tb * 8 + it;
                float a0 = 0, a1 = 0, a2 = 0, a3 = 0;
                #pragma unroll 4
                for (int c = 0; c < 192; ++c) {
                    float xv = bf2f(xsb[t][c]);
                    float4 w = *(const float4*)(wcol + c * 768);
                    a0 += xv * w.x; a1 += xv * w.y; a2 += xv * w.z; a3 += xv * w.w;
                }
                int jb = cn * 128 + jj;
                a0 = gelu_exact(a0 + fc1_b[jb]);
                a1 = gelu_exact(a1 + fc1_b[jb + 1]);
                a2 = gelu_exact(a2 + fc1_b[jb + 2]);
                a3 = gelu_exact(a3 + fc1_b[jb + 3]);
                hs[t * 130 + jj]     = f2bf(a0);
                hs[t * 130 + jj + 1] = f2bf(a1);
                hs[t * 130 + jj + 2] = f2bf(a2);
                hs[t * 130 + jj + 3] = f2bf(a3);
            }
        }
        __syncthreads();
        {
            const float* wbase = fc2_w + zz * 48;
            for (int jj = 0; jj < 128; ++jj) {
                float hv = bf2f(hs[zt * 130 + jj]);
                const float* wrow = wbase + (cn * 128 + jj) * 192;
                #pragma unroll
                for (int j4 = 0; j4 < 48; j4 += 4) {
                    float4 w = *(const float4*)(wrow + j4);
                    acc2[j4]     += hv * w.x;
                    acc2[j4 + 1] += hv * w.y;
                    acc2[j4 + 2] += hv * w.z;
                    acc2[j4 + 3] += hv * w.w;
                }
            }
        }
        __syncthreads();
    }

    // ---- final: out = xh2 + mlp + fc2_b, transposed (B,C,H,W) f32 write ----
    {
        float* obase = out + b * (192 * 65536) + gh * 256 + gw;
        #pragma unroll 4
        for (int j = 0; j < 48; ++j) {
            int c = zz * 48 + j;
            obase[c * 65536] = acc[j] + acc2[j] + fc2_b[c];
        }
    }
}

extern "C" void kernel_launch(void* const* d_in, const int* in_sizes, int n_in,
                              void* d_out, int out_size, void* d_ws, size_t ws_size,
                              hipStream_t stream) {
    const float* x      = (const float*)d_in[0];
    const float* bpe    = (const float*)d_in[1];
    const float* ln1_w  = (const float*)d_in[2];
    const float* ln1_b  = (const float*)d_in[3];
    const float* qkv_w  = (const float*)d_in[4];
    const float* qkv_b  = (const float*)d_in[5];
    const float* bpe_w  = (const float*)d_in[6];
    const float* bpe_b  = (const float*)d_in[7];
    const float* proj_w = (const float*)d_in[8];
    const float* proj_b = (const float*)d_in[9];
    const float* ln2_w  = (const float*)d_in[10];
    const float* ln2_b  = (const float*)d_in[11];
    const float* fc1_w  = (const float*)d_in[12];
    const float* fc1_b  = (const float*)d_in[13];
    const float* fc2_w  = (const float*)d_in[14];
    const float* fc2_b  = (const float*)d_in[15];

    fused_block_kernel<<<NWIN, 256, 0, stream>>>(
        x, bpe, ln1_w, ln1_b, qkv_w, qkv_b, bpe_w, bpe_b, proj_w, proj_b,
        ln2_w, ln2_b, fc1_w, fc1_b, fc2_w, fc2_b, (float*)d_out);
}

// Round 3
// 1236.624 us; speedup vs baseline: 11.4045x; 11.4045x over previous
//
#include <hip/hip_runtime.h>

// Problem: B=4, DIM=192, H=W=256, HEADS=6, d=32, WS=8 -> 4096 windows x 64 tokens
// One block per window, 256 threads = 4 waves.

typedef __attribute__((ext_vector_type(8))) short short8;   // 8 bf16 (4 VGPR)
typedef __attribute__((ext_vector_type(4))) float floatx4;  // MFMA C/D frag

#define MFMA16(a, b, c) __builtin_amdgcn_mfma_f32_16x16x32_bf16((a), (b), (c), 0, 0, 0)

__device__ __forceinline__ float bf2f(unsigned short u) {
    return __uint_as_float(((unsigned int)u) << 16);
}
__device__ __forceinline__ unsigned short f2bf(float f) {
    unsigned int x = __float_as_uint(f);
    x += 0x7fffu + ((x >> 16) & 1u);
    return (unsigned short)(x >> 16);
}
__device__ __forceinline__ float gelu_exact(float x) {
    return 0.5f * x * (1.0f + erff(x * 0.70710678118654752f));
}

// bf16 transposed-weight layout in workspace (element offsets, shorts):
// qkvT [576][192], bpeT [384][32], projT [192][192], fc1T [768][192], fc2T [192][768]
#define QKVT  0
#define BPET  110592
#define PROJT 122880
#define FC1T  159744
#define FC2T  307200
#define WTOT  454656

__global__ void convert_weights_kernel(
    const float* __restrict__ qkv_w, const float* __restrict__ bpe_w,
    const float* __restrict__ proj_w, const float* __restrict__ fc1_w,
    const float* __restrict__ fc2_w, unsigned short* __restrict__ wt)
{
    int i = blockIdx.x * 256 + threadIdx.x;
    if (i < 110592) { int n = i / 192, k = i % 192; wt[QKVT + i] = f2bf(qkv_w[k * 576 + n]); return; }
    i -= 110592;
    if (i < 12288)  { int n = i / 32,  k = i % 32;  wt[BPET + i] = f2bf(bpe_w[k * 384 + n]); return; }
    i -= 12288;
    if (i < 36864)  { int n = i / 192, k = i % 192; wt[PROJT + i] = f2bf(proj_w[k * 192 + n]); return; }
    i -= 36864;
    if (i < 147456) { int n = i / 192, k = i % 192; wt[FC1T + i] = f2bf(fc1_w[k * 768 + n]); return; }
    i -= 147456;
    if (i < 147456) { int n = i / 768, k = i % 768; wt[FC2T + i] = f2bf(fc2_w[k * 192 + n]); return; }
}

// LDS byte offsets (all 16B aligned), total 70144 B -> 2 blocks/CU
#define OFF_XN   0       // [64][200] bf16  (xn -> later xn2)           25600
#define OFF_QC   25600   // [64][72] bf16   ([q*s|bq*s])                 9216
#define OFF_KC   34816   // [64][72] bf16   ([k|bk])                     9216
#define OFF_VT   44032   // [32][72] bf16   (V^T per head)               4608
#define OFF_P    48640   // [64][72] bf16   (probabilities)              9216
// phase-B overlays at OFF_QC (32256 B region): x_raw [64][200] bf16, h chunk
// [64][200] bf16, out staging [64][100] f32 (each 25600 B)
#define OFF_BPE  57856   // [64][40] bf16                                5120
#define OFF_O    62976   // [64][40] bf16  (per-head attn out)           5120
#define OFF_SR   68096   // [64][4] f32    LN2 partial sums              1024
#define OFF_SR2  69120   // [64][4] f32                                  1024
#define LDS_TOT  70144

__global__ __launch_bounds__(256, 2) void fused_mfma_kernel(
    const float* __restrict__ x,      // (4,192,256,256)
    const float* __restrict__ bpe,    // (4,32,256,256)
    const float* __restrict__ ln1_w, const float* __restrict__ ln1_b,
    const float* __restrict__ qkv_b,  // (576)
    const float* __restrict__ bpe_b,  // (384)
    const float* __restrict__ proj_b, // (192)
    const float* __restrict__ ln2_w, const float* __restrict__ ln2_b,
    const float* __restrict__ fc1_b,  // (768)
    const float* __restrict__ fc2_b,  // (192)
    const unsigned short* __restrict__ wt, // bf16 transposed weights
    float* __restrict__ out)          // (4,192,256,256)
{
    __shared__ __align__(16) unsigned char smem[LDS_TOT];
    unsigned short* xn    = (unsigned short*)(smem + OFF_XN);
    unsigned short* qc    = (unsigned short*)(smem + OFF_QC);
    unsigned short* kc    = (unsigned short*)(smem + OFF_KC);
    unsigned short* vt    = (unsigned short*)(smem + OFF_VT);
    unsigned short* Pb    = (unsigned short*)(smem + OFF_P);
    unsigned short* bpe_s = (unsigned short*)(smem + OFF_BPE);
    unsigned short* Ob    = (unsigned short*)(smem + OFF_O);
    float*          sred  = (float*)(smem + OFF_SR);
    float*          s2red = (float*)(smem + OFF_SR2);
    unsigned short* xraw  = (unsigned short*)(smem + OFF_QC); // phase-B overlay
    unsigned short* hbuf  = (unsigned short*)(smem + OFF_QC);
    float*          stg   = (float*)(smem + OFF_QC);

    const int tid  = threadIdx.x;
    const int lane = tid & 63;
    const int wv   = tid >> 6;
    const int quad = lane >> 4;
    const int col  = lane & 15;

    const int wid = blockIdx.x;
    const int b   = wid >> 10;
    const int rem = wid & 1023;
    const int h0  = (rem >> 5) << 3;
    const int w0  = (rem & 31) << 3;

    const float SCALE = 0.17677669529663687f; // 1/sqrt(32)

    // ---------------- Phase 0: load + LN1 ----------------
    for (int e = tid; e < 64 * 192; e += 256) {
        int t = e & 63, c = e >> 6;
        xn[t * 200 + c] = f2bf(x[b * (192 * 65536) + c * 65536 +
                                 (h0 + (t >> 3)) * 256 + (w0 + (t & 7))]);
    }
    for (int e = tid; e < 64 * 32; e += 256) {
        int t = e & 63, c = e >> 6;
        bpe_s[t * 40 + c] = f2bf(bpe[b * (32 * 65536) + c * 65536 +
                                     (h0 + (t >> 3)) * 256 + (w0 + (t & 7))]);
    }
    __syncthreads();
    {
        int t = tid >> 2, sub = tid & 3, c0 = sub * 48;
        float s = 0.f, s2 = 0.f;
        for (int c = c0; c < c0 + 48; ++c) {
            float v = bf2f(xn[t * 200 + c]);
            s += v; s2 += v * v;
        }
        s  += __shfl_xor(s, 1);  s  += __shfl_xor(s, 2);
        s2 += __shfl_xor(s2, 1); s2 += __shfl_xor(s2, 2);
        float m    = s * (1.0f / 192.0f);
        float var  = s2 * (1.0f / 192.0f) - m * m;
        float rstd = rsqrtf(var + 1e-5f);
        for (int c = c0; c < c0 + 48; ++c) {
            float v = bf2f(xn[t * 200 + c]);
            xn[t * 200 + c] = f2bf((v - m) * rstd * ln1_w[c] + ln1_b[c]);
        }
    }
    __syncthreads();

    // proj accumulator: wave wv owns channels [48wv, 48wv+48), all 64 tokens
    floatx4 Cp[3][4];
    #pragma unroll
    for (int nt = 0; nt < 3; ++nt)
        #pragma unroll
        for (int mt = 0; mt < 4; ++mt)
            Cp[nt][mt] = (floatx4){0.f, 0.f, 0.f, 0.f};

    // ---------------- Phase A: per-head attention ----------------
    for (int h = 0; h < 6; ++h) {
        const int h32 = h * 32;

        // ---- A1: wave-specialized qc / kc / v / bqk GEMMs ----
        if (wv < 2) {
            // wv==0: q (scaled) ; wv==1: k
            const int rbase = (wv == 0) ? h32 : 192 + h32;
            floatx4 C[2][4];
            #pragma unroll
            for (int nt = 0; nt < 2; ++nt)
                #pragma unroll
                for (int mt = 0; mt < 4; ++mt) C[nt][mt] = (floatx4){0.f,0.f,0.f,0.f};
            #pragma unroll
            for (int ks = 0; ks < 6; ++ks) {
                short8 a[4];
                #pragma unroll
                for (int mt = 0; mt < 4; ++mt)
                    a[mt] = *(const short8*)(xn + (mt * 16 + col) * 200 + ks * 32 + quad * 8);
                #pragma unroll
                for (int nt = 0; nt < 2; ++nt) {
                    short8 bf = *(const short8*)(wt + QKVT + (rbase + nt * 16 + col) * 192 + ks * 32 + quad * 8);
                    #pragma unroll
                    for (int mt = 0; mt < 4; ++mt) C[nt][mt] = MFMA16(a[mt], bf, C[nt][mt]);
                }
            }
            unsigned short* dst = (wv == 0) ? qc : kc;
            const float sc = (wv == 0) ? SCALE : 1.0f;
            #pragma unroll
            for (int nt = 0; nt < 2; ++nt) {
                float bias = qkv_b[rbase + nt * 16 + col];
                #pragma unroll
                for (int mt = 0; mt < 4; ++mt)
                    #pragma unroll
                    for (int r = 0; r < 4; ++r)
                        dst[(mt * 16 + quad * 4 + r) * 72 + nt * 16 + col] =
                            f2bf((C[nt][mt][r] + bias) * sc);
            }
        } else if (wv == 2) {
            // v -> VT (transposed store)
            const int rbase = 384 + h32;
            floatx4 C[2][4];
            #pragma unroll
            for (int nt = 0; nt < 2; ++nt)
                #pragma unroll
                for (int mt = 0; mt < 4; ++mt) C[nt][mt] = (floatx4){0.f,0.f,0.f,0.f};
            #pragma unroll
            for (int ks = 0; ks < 6; ++ks) {
                short8 a[4];
                #pragma unroll
                for (int mt = 0; mt < 4; ++mt)
                    a[mt] = *(const short8*)(xn + (mt * 16 + col) * 200 + ks * 32 + quad * 8);
                #pragma unroll
                for (int nt = 0; nt < 2; ++nt) {
                    short8 bf = *(const short8*)(wt + QKVT + (rbase + nt * 16 + col) * 192 + ks * 32 + quad * 8);
                    #pragma unroll
                    for (int mt = 0; mt < 4; ++mt) C[nt][mt] = MFMA16(a[mt], bf, C[nt][mt]);
                }
            }
            #pragma unroll
            for (int nt = 0; nt < 2; ++nt) {
                float bias = qkv_b[rbase + nt * 16 + col];
                #pragma unroll
                for (int mt = 0; mt < 4; ++mt)
                    #pragma unroll
                    for (int r = 0; r < 4; ++r)
                        vt[(nt * 16 + col) * 72 + mt * 16 + quad * 4 + r] =
                            f2bf(C[nt][mt][r] + bias);
            }
        } else {
            // wv==3: bq (scaled) -> qc cols 32..63 ; bk -> kc cols 32..63
            short8 ab[4];
            #pragma unroll
            for (int mt = 0; mt < 4; ++mt)
                ab[mt] = *(const short8*)(bpe_s + (mt * 16 + col) * 40 + quad * 8);
            floatx4 C[2][2][4];
            #pragma unroll
            for (int qk = 0; qk < 2; ++qk)
                #pragma unroll
                for (int nt = 0; nt < 2; ++nt)
                    #pragma unroll
                    for (int mt = 0; mt < 4; ++mt) C[qk][nt][mt] = (floatx4){0.f,0.f,0.f,0.f};
            #pragma unroll
            for (int qk = 0; qk < 2; ++qk) {
                const int rbase = (qk ? 192 : 0) + h32;
                #pragma unroll
                for (int nt = 0; nt < 2; ++nt) {
                    short8 bf = *(const short8*)(wt + BPET + (rbase + nt * 16 + col) * 32 + quad * 8);
                    #pragma unroll
                    for (int mt = 0; mt < 4; ++mt) C[qk][nt][mt] = MFMA16(ab[mt], bf, C[qk][nt][mt]);
                }
            }
            #pragma unroll
            for (int qk = 0; qk < 2; ++qk) {
                unsigned short* dst = qk ? kc : qc;
                const float sc = qk ? 1.0f : SCALE;
                const int rbase = (qk ? 192 : 0) + h32;
                #pragma unroll
                for (int nt = 0; nt < 2; ++nt) {
                    float bias = bpe_b[rbase + nt * 16 + col];
                    #pragma unroll
                    for (int mt = 0; mt < 4; ++mt)
                        #pragma unroll
                        for (int r = 0; r < 4; ++r)
                            dst[(mt * 16 + quad * 4 + r) * 72 + 32 + nt * 16 + col] =
                                f2bf((C[qk][nt][mt][r] + bias) * sc);
                }
            }
        }
        __syncthreads();

        // ---- A2: S = qc @ kc^T (K=64), in-register softmax, write P ----
        {
            const int m0 = wv * 16;
            short8 a0 = *(const short8*)(qc + (m0 + col) * 72 + quad * 8);
            short8 a1 = *(const short8*)(qc + (m0 + col) * 72 + 32 + quad * 8);
            floatx4 Cs[4];
            #pragma unroll
            for (int nt = 0; nt < 4; ++nt) {
                short8 b0 = *(const short8*)(kc + (nt * 16 + col) * 72 + quad * 8);
                short8 b1 = *(const short8*)(kc + (nt * 16 + col) * 72 + 32 + quad * 8);
                floatx4 z = (floatx4){0.f, 0.f, 0.f, 0.f};
                z = MFMA16(a0, b0, z);
                z = MFMA16(a1, b1, z);
                Cs[nt] = z;
            }
            #pragma unroll
            for (int r = 0; r < 4; ++r) {
                float mx = fmaxf(fmaxf(Cs[0][r], Cs[1][r]), fmaxf(Cs[2][r], Cs[3][r]));
                mx = fmaxf(mx, __shfl_xor(mx, 1));
                mx = fmaxf(mx, __shfl_xor(mx, 2));
                mx = fmaxf(mx, __shfl_xor(mx, 4));
                mx = fmaxf(mx, __shfl_xor(mx, 8));
                float p0 = __expf(Cs[0][r] - mx), p1 = __expf(Cs[1][r] - mx);
                float p2 = __expf(Cs[2][r] - mx), p3 = __expf(Cs[3][r] - mx);
                float sum = p0 + p1 + p2 + p3;
                sum += __shfl_xor(sum, 1);
                sum += __shfl_xor(sum, 2);
                sum += __shfl_xor(sum, 4);
                sum += __shfl_xor(sum, 8);
                float inv = 1.0f / sum;
                Cs[0][r] = p0 * inv; Cs[1][r] = p1 * inv;
                Cs[2][r] = p2 * inv; Cs[3][r] = p3 * inv;
            }
            #pragma unroll
            for (int nt = 0; nt < 4; ++nt)
                #pragma unroll
                for (int r = 0; r < 4; ++r)
                    Pb[(m0 + quad * 4 + r) * 72 + nt * 16 + col] = f2bf(Cs[nt][r]);
        }
        __syncthreads();

        // ---- A3: O = P @ V (K=64) ----
        {
            const int m0 = wv * 16;
            short8 p0 = *(const short8*)(Pb + (m0 + col) * 72 + quad * 8);
            short8 p1 = *(const short8*)(Pb + (m0 + col) * 72 + 32 + quad * 8);
            #pragma unroll
            for (int nt = 0; nt < 2; ++nt) {
                short8 b0 = *(const short8*)(vt + (nt * 16 + col) * 72 + quad * 8);
                short8 b1 = *(const short8*)(vt + (nt * 16 + col) * 72 + 32 + quad * 8);
                floatx4 z = (floatx4){0.f, 0.f, 0.f, 0.f};
                z = MFMA16(p0, b0, z);
                z = MFMA16(p1, b1, z);
                #pragma unroll
                for (int r = 0; r < 4; ++r)
                    Ob[(m0 + quad * 4 + r) * 40 + nt * 16 + col] = f2bf(z[r]);
            }
        }
        __syncthreads();

        // ---- A4: proj accumulation (N-split, K=32 slice per head) ----
        {
            short8 ao[4];
            #pragma unroll
            for (int mt = 0; mt < 4; ++mt)
                ao[mt] = *(const short8*)(Ob + (mt * 16 + col) * 40 + quad * 8);
            #pragma unroll
            for (int nt = 0; nt < 3; ++nt) {
                short8 bf = *(const short8*)(wt + PROJT + (wv * 48 + nt * 16 + col) * 192 + h32 + quad * 8);
                #pragma unroll
                for (int mt = 0; mt < 4; ++mt) Cp[nt][mt] = MFMA16(ao[mt], bf, Cp[nt][mt]);
            }
        }
        // no barrier needed before next head's A1 (see hazard analysis)
    }

    // ---------------- Phase B ----------------
    // B1: reload raw x (coalesced) -> xraw overlay; xh2 = Cp + proj_b + x
    for (int e = tid; e < 64 * 192; e += 256) {
        int t = e & 63, c = e >> 6;
        xraw[t * 200 + c] = f2bf(x[b * (192 * 65536) + c * 65536 +
                                   (h0 + (t >> 3)) * 256 + (w0 + (t & 7))]);
    }
    __syncthreads();

    float xh2a[3][4][4];
    {
        float pbv[3];
        #pragma unroll
        for (int nt = 0; nt < 3; ++nt) pbv[nt] = proj_b[wv * 48 + nt * 16 + col];
        #pragma unroll
        for (int nt = 0; nt < 3; ++nt)
            #pragma unroll
            for (int mt = 0; mt < 4; ++mt)
                #pragma unroll
                for (int r = 0; r < 4; ++r) {
                    int t = mt * 16 + quad * 4 + r;
                    int c = wv * 48 + nt * 16 + col;
                    xh2a[nt][mt][r] = Cp[nt][mt][r] + pbv[nt] + bf2f(xraw[t * 200 + c]);
                }
    }

    // B2: LN2 (cross-wave partial sums via LDS), write xn2 into xn buffer
    #pragma unroll
    for (int mt = 0; mt < 4; ++mt)
        #pragma unroll
        for (int r = 0; r < 4; ++r) {
            float s  = xh2a[0][mt][r] + xh2a[1][mt][r] + xh2a[2][mt][r];
            float s2 = xh2a[0][mt][r] * xh2a[0][mt][r] +
                       xh2a[1][mt][r] * xh2a[1][mt][r] +
                       xh2a[2][mt][r] * xh2a[2][mt][r];
            s  += __shfl_xor(s, 1);  s  += __shfl_xor(s, 2);
            s  += __shfl_xor(s, 4);  s  += __shfl_xor(s, 8);
            s2 += __shfl_xor(s2, 1); s2 += __shfl_xor(s2, 2);
            s2 += __shfl_xor(s2, 4); s2 += __shfl_xor(s2, 8);
            if (col == 0) {
                int t = mt * 16 + quad * 4 + r;
                sred[t * 4 + wv] = s;
                s2red[t * 4 + wv] = s2;
            }
        }
    __syncthreads();
    {
        float lw[3], lb[3];
        #pragma unroll
        for (int nt = 0; nt < 3; ++nt) {
            lw[nt] = ln2_w[wv * 48 + nt * 16 + col];
            lb[nt] = ln2_b[wv * 48 + nt * 16 + col];
        }
        #pragma unroll
        for (int mt = 0; mt < 4; ++mt)
            #pragma unroll
            for (int r = 0; r < 4; ++r) {
                int t = mt * 16 + quad * 4 + r;
                float S  = sred[t * 4] + sred[t * 4 + 1] + sred[t * 4 + 2] + sred[t * 4 + 3];
                float S2 = s2red[t * 4] + s2red[t * 4 + 1] + s2red[t * 4 + 2] + s2red[t * 4 + 3];
                float m    = S * (1.0f / 192.0f);
                float var  = S2 * (1.0f / 192.0f) - m * m;
                float rstd = rsqrtf(var + 1e-5f);
                #pragma unroll
                for (int nt = 0; nt < 3; ++nt) {
                    int c = wv * 48 + nt * 16 + col;
                    xn[t * 200 + c] = f2bf((xh2a[nt][mt][r] - m) * rstd * lw[nt] + lb[nt]);
                }
            }
    }
    __syncthreads();

    // B3: MLP in 4 chunks of 192 hidden units; fc2 accumulates in Cf
    floatx4 Cf[3][4];
    #pragma unroll
    for (int nt = 0; nt < 3; ++nt)
        #pragma unroll
        for (int mt = 0; mt < 4; ++mt) Cf[nt][mt] = (floatx4){0.f, 0.f, 0.f, 0.f};

    for (int cn = 0; cn < 4; ++cn) {
        // fc1 chunk + gelu -> hbuf
        {
            floatx4 C1[3][4];
            #pragma unroll
            for (int nt = 0; nt < 3; ++nt)
                #pragma unroll
                for (int mt = 0; mt < 4; ++mt) C1[nt][mt] = (floatx4){0.f, 0.f, 0.f, 0.f};
            #pragma unroll
            for (int ks = 0; ks < 6; ++ks) {
                short8 a[4];
                #pragma unroll
                for (int mt = 0; mt < 4; ++mt)
                    a[mt] = *(const short8*)(xn + (mt * 16 + col) * 200 + ks * 32 + quad * 8);
                #pragma unroll
                for (int nt = 0; nt < 3; ++nt) {
                    int ng = cn * 192 + wv * 48 + nt * 16 + col;
                    short8 bf = *(const short8*)(wt + FC1T + ng * 192 + ks * 32 + quad * 8);
                    #pragma unroll
                    for (int mt = 0; mt < 4; ++mt) C1[nt][mt] = MFMA16(a[mt], bf, C1[nt][mt]);
                }
            }
            #pragma unroll
            for (int nt = 0; nt < 3; ++nt) {
                float bias = fc1_b[cn * 192 + wv * 48 + nt * 16 + col];
                #pragma unroll
                for (int mt = 0; mt < 4; ++mt)
                    #pragma unroll
                    for (int r = 0; r < 4; ++r)
                        hbuf[(mt * 16 + quad * 4 + r) * 200 + wv * 48 + nt * 16 + col] =
                            f2bf(gelu_exact(C1[nt][mt][r] + bias));
            }
        }
        __syncthreads();
        // fc2 accumulate over this chunk (K=192)
        {
            #pragma unroll
            for (int ks = 0; ks < 6; ++ks) {
                short8 a[4];
                #pragma unroll
                for (int mt = 0; mt < 4; ++mt)
                    a[mt] = *(const short8*)(hbuf + (mt * 16 + col) * 200 + ks * 32 + quad * 8);
                #pragma unroll
                for (int nt = 0; nt < 3; ++nt) {
                    short8 bf = *(const short8*)(wt + FC2T + (wv * 48 + nt * 16 + col) * 768 +
                                                 cn * 192 + ks * 32 + quad * 8);
                    #pragma unroll
                    for (int mt = 0; mt < 4; ++mt) Cf[nt][mt] = MFMA16(a[mt], bf, Cf[nt][mt]);
                }
            }
        }
        __syncthreads();
    }

    // B4: out = xh2 + mlp + fc2_b, staged through LDS (f32, 2 passes)
    float fbv[3];
    #pragma unroll
    for (int nt = 0; nt < 3; ++nt) fbv[nt] = fc2_b[wv * 48 + nt * 16 + col];

    // pass 0: channels 0..95 (waves 0,1)
    if (wv < 2) {
        #pragma unroll
        for (int nt = 0; nt < 3; ++nt)
            #pragma unroll
            for (int mt = 0; mt < 4; ++mt)
                #pragma unroll
                for (int r = 0; r < 4; ++r) {
                    int t = mt * 16 + quad * 4 + r;
                    int cl = wv * 48 + nt * 16 + col;
                    stg[t * 100 + cl] = xh2a[nt][mt][r] + Cf[nt][mt][r] + fbv[nt];
                }
    }
    __syncthreads();
    for (int e = tid; e < 64 * 96; e += 256) {
        int t = e & 63, cl = e >> 6;
        out[((b * 192 + cl) << 16) + (h0 + (t >> 3)) * 256 + (w0 + (t & 7))] = stg[t * 100 + cl];
    }
    __syncthreads();
    // pass 1: channels 96..191 (waves 2,3)
    if (wv >= 2) {
        #pragma unroll
        for (int nt = 0; nt < 3; ++nt)
            #pragma unroll
            for (int mt = 0; mt < 4; ++mt)
                #pragma unroll
                for (int r = 0; r < 4; ++r) {
                    int t = mt * 16 + quad * 4 + r;
                    int cl = (wv - 2) * 48 + nt * 16 + col;
                    stg[t * 100 + cl] = xh2a[nt][mt][r] + Cf[nt][mt][r] + fbv[nt];
                }
    }
    __syncthreads();
    for (int e = tid; e < 64 * 96; e += 256) {
        int t = e & 63, cl = e >> 6;
        out[((b * 192 + 96 + cl) << 16) + (h0 + (t >> 3)) * 256 + (w0 + (t & 7))] = stg[t * 100 + cl];
    }
}

extern "C" void kernel_launch(void* const* d_in, const int* in_sizes, int n_in,
                              void* d_out, int out_size, void* d_ws, size_t ws_size,
                              hipStream_t stream) {
    const float* x      = (const float*)d_in[0];
    const float* bpe    = (const float*)d_in[1];
    const float* ln1_w  = (const float*)d_in[2];
    const float* ln1_b  = (const float*)d_in[3];
    const float* qkv_w  = (const float*)d_in[4];
    const float* qkv_b  = (const float*)d_in[5];
    const float* bpe_w  = (const float*)d_in[6];
    const float* bpe_b  = (const float*)d_in[7];
    const float* proj_w = (const float*)d_in[8];
    const float* proj_b = (const float*)d_in[9];
    const float* ln2_w  = (const float*)d_in[10];
    const float* ln2_b  = (const float*)d_in[11];
    const float* fc1_w  = (const float*)d_in[12];
    const float* fc1_b  = (const float*)d_in[13];
    const float* fc2_w  = (const float*)d_in[14];
    const float* fc2_b  = (const float*)d_in[15];

    unsigned short* wt = (unsigned short*)d_ws; // 909 KB bf16 transposed weights

    convert_weights_kernel<<<(WTOT + 255) / 256, 256, 0, stream>>>(
        qkv_w, bpe_w, proj_w, fc1_w, fc2_w, wt);
    fused_mfma_kernel<<<4096, 256, 0, stream>>>(
        x, bpe, ln1_w, ln1_b, qkv_b, bpe_b, proj_b, ln2_w, ln2_b,
        fc1_b, fc2_b, wt, (float*)d_out);
}